// Round 7
// baseline (273.729 us; speedup 1.0000x reference)
//
#include <hip/hip_runtime.h>
#include <hip/hip_fp16.h>
#include <math.h>

#define N_NODES 50000
#define N_EDGES 800000
#define F_IN    64
#define H_DIM   128
#define N_GRAPH 512
#define NEG_SLOPE 0.2f

typedef __attribute__((ext_vector_type(8))) short short8;   // 8 bf16 (4 VGPRs)
typedef __attribute__((ext_vector_type(4))) float f32x4;
typedef __attribute__((ext_vector_type(2))) float f32x2;
typedef _Float16 h2 __attribute__((ext_vector_type(2)));    // half2 (v_pk_*_f16)

// ---- counting-sort geometry: bins of 256 dst nodes, 2048-edge bin1 blocks
#define NBIN   196                      // ceil(50000/256)
#define NBLK1  391                      // ceil(800000/2048)
#define NBB    (NBIN * NBLK1)           // 76636 (bin-major count matrix)
#define SCANA_NB ((NBB + 255) / 256)    // 300

// fp32 -> bf16(hi) + bf16(lo), truncation split (residual ~2^-16 relative)
__device__ __forceinline__ void bsplit(float v, unsigned short& h, unsigned short& l) {
    unsigned u = __float_as_uint(v);
    h = (unsigned short)(u >> 16);
    float hf = __uint_as_float(u & 0xFFFF0000u);
    float r = v - hf;
    l = (unsigned short)(__float_as_uint(r) >> 16);
}
__device__ __forceinline__ float bjoin(unsigned short h, unsigned short l) {
    return __uint_as_float(((unsigned)h) << 16) + __uint_as_float(((unsigned)l) << 16);
}

// ------------------- prep: prepW(frag-major swizzle) | bin1 (LDS histogram)
#define NB_PW 192
__global__ __launch_bounds__(256) void k_prep(
    const float* __restrict__ Wl1, const float* __restrict__ Wr1,
    const float* __restrict__ Wl2, const float* __restrict__ Wr2,
    const int* __restrict__ dst,
    unsigned short* __restrict__ WThi, unsigned short* __restrict__ WTlo,
    int* __restrict__ lrank, int* __restrict__ bcnt)
{
    __shared__ int cnt_lds[NBIN];
    const int bid = blockIdx.x, tid = threadIdx.x;
    if (bid < NB_PW) {
        int idx = bid * 256 + tid;   // 0..49151
        if (idx < 49152) {
            const float* W; int K, li, base, o;
            if (idx < 8192)       { W = Wl1; K = 64;  li = idx;         base = 0;     o = 0; }
            else if (idx < 16384) { W = Wr1; K = 64;  li = idx - 8192;  base = 0;     o = 1; }
            else if (idx < 32768) { W = Wl2; K = 128; li = idx - 16384; base = 16384; o = 0; }
            else                  { W = Wr2; K = 128; li = idx - 32768; base = 16384; o = 1; }
            int c = li / K, k = li - c * K;
            int g = c >> 4, n16 = c & 15;
            int kkblk = k >> 5, quad = (k >> 3) & 3, j = k & 7;
            int off = base + kkblk * 8192 + o * 4096 + g * 512 + (quad * 16 + n16) * 8 + j;
            unsigned short h, l;
            bsplit(W[k * 128 + c], h, l);
            WThi[off] = h; WTlo[off] = l;
        }
    } else {
        const int b2 = bid - NB_PW;    // 0..390
        if (tid < NBIN) cnt_lds[tid] = 0;
        __syncthreads();
#pragma unroll
        for (int it = 0; it < 8; ++it) {
            int e = b2 * 2048 + it * 256 + tid;
            if (e < N_EDGES) {
                int d = dst[e];
                lrank[e] = atomicAdd(&cnt_lds[d >> 8], 1);
            }
        }
        __syncthreads();
        if (tid < NBIN) bcnt[tid * NBLK1 + b2] = cnt_lds[tid];
    }
}

// ---------------------------------------------------------------- scans
__global__ __launch_bounds__(256) void k_scanA(const int* __restrict__ bcnt,
                                               int* __restrict__ bbase,
                                               int* __restrict__ partials) {
    __shared__ int s[256];
    int t = threadIdx.x, gid = blockIdx.x * 256 + t;
    int v = (gid < NBB) ? bcnt[gid] : 0;
    s[t] = v;
    __syncthreads();
    for (int off = 1; off < 256; off <<= 1) {
        int x = (t >= off) ? s[t - off] : 0;
        __syncthreads();
        s[t] += x;
        __syncthreads();
    }
    if (gid < NBB) bbase[gid] = s[t] - v;
    if (t == 255) partials[blockIdx.x] = s[t];
}

__global__ __launch_bounds__(256) void k_scanB(int* __restrict__ bbase,
                                               const int* __restrict__ partials) {
    __shared__ int red[256];
    const int t = threadIdx.x, b = blockIdx.x;
    int acc = 0;
    for (int j = t; j < b; j += 256) acc += partials[j];
    red[t] = acc;
    __syncthreads();
    for (int off = 128; off > 0; off >>= 1) {
        if (t < off) red[t] += red[t + off];
        __syncthreads();
    }
    int base = red[0];
    int gid = b * 256 + t;
    if (gid < NBB) bbase[gid] += base;
}

// scatter edges into bin-sorted order; pack src (16b) | dst&255 (8b)
__global__ __launch_bounds__(256) void k_bin2(const int* __restrict__ src,
                                              const int* __restrict__ dst,
                                              const int* __restrict__ lrank,
                                              const int* __restrict__ bbase,
                                              unsigned* __restrict__ ebin) {
    int e = blockIdx.x * 256 + threadIdx.x;
    if (e < N_EDGES) {
        int d = dst[e];
        int pos = bbase[(d >> 8) * NBLK1 + (e >> 11)] + lrank[e];
        ebin[pos] = (unsigned)src[e] | ((unsigned)(d & 255) << 16);
    }
}

// per-bin: exact per-node counts (LDS) -> in-bin scan -> offsets + col_src.
__global__ __launch_bounds__(256) void k_bin3(const unsigned* __restrict__ ebin,
                                              const int* __restrict__ bbase,
                                              int* __restrict__ offsets,
                                              int* __restrict__ col_src) {
    __shared__ int cnt2[256];
    __shared__ int sc[256];
    __shared__ int cur[256];
    const int b = blockIdx.x, t = threadIdx.x;
    const int lo = bbase[b * NBLK1];
    const int hi = (b == NBIN - 1) ? N_EDGES : bbase[(b + 1) * NBLK1];

    cnt2[t] = 0;
    __syncthreads();
    for (int pos = lo + t; pos < hi; pos += 256) {
        unsigned u = ebin[pos];
        atomicAdd(&cnt2[u >> 16], 1);
    }
    __syncthreads();
    int v = cnt2[t];
    sc[t] = v;
    __syncthreads();
    for (int off = 1; off < 256; off <<= 1) {
        int x = (t >= off) ? sc[t - off] : 0;
        __syncthreads();
        sc[t] += x;
        __syncthreads();
    }
    int myoff = lo + sc[t] - v;            // exclusive in-bin prefix + bin base
    int node = b * 256 + t;
    if (node < N_NODES) offsets[node] = myoff;
    cur[t] = myoff;
    if (b == NBIN - 1 && t == 0) offsets[N_NODES] = N_EDGES;
    __syncthreads();
    for (int pos = lo + t; pos < hi; pos += 256) {
        unsigned u = ebin[pos];
        int p = atomicAdd(&cur[u >> 16], 1);
        col_src[p] = (int)(u & 0xFFFFu);
    }
}

// ---------------------------------------------------------------- MFMA GEMM
#define APITCH 40
#define GB_GEMM ((N_NODES + 63) / 64)   // 782

template <bool F32SRC>
__device__ __forceinline__ void gemm_body(
    unsigned short* __restrict__ Ah, unsigned short* __restrict__ Al,
    const float* __restrict__ Xf,
    const unsigned short* __restrict__ Xhi, const unsigned short* __restrict__ Xlo,
    const unsigned short* __restrict__ WThi, const unsigned short* __restrict__ WTlo,
    const float* __restrict__ bl, const float* __restrict__ br,
    unsigned short* __restrict__ OL, unsigned short* __restrict__ OR_,
    int K, int blk)
{
    const int tid  = threadIdx.x;
    const int wv   = tid >> 6;        // wave: cols [wv*32, wv*32+32)
    const int lane = tid & 63;
    const int n16  = lane & 15;
    const int quad = lane >> 4;
    const int row0 = blk * 64;

    f32x4 acc[4][2][2];               // [rtile][ctile][out]
#pragma unroll
    for (int r = 0; r < 4; ++r)
#pragma unroll
        for (int c = 0; c < 2; ++c)
#pragma unroll
            for (int o = 0; o < 2; ++o) acc[r][c][o] = (f32x4)0.f;

    for (int kk = 0; kk < K; kk += 32) {
        if (F32SRC) {
            int r = tid >> 2, sub = tid & 3;
            int grow = row0 + r;
            float4 v0 = make_float4(0.f, 0.f, 0.f, 0.f);
            float4 v1 = make_float4(0.f, 0.f, 0.f, 0.f);
            if (grow < N_NODES) {
                const float* s = Xf + (size_t)grow * K + kk + sub * 8;
                v0 = *(const float4*)s;
                v1 = *(const float4*)(s + 4);
            }
            union { unsigned short s[8]; uint4 u; } Hh, Ll;
            bsplit(v0.x, Hh.s[0], Ll.s[0]); bsplit(v0.y, Hh.s[1], Ll.s[1]);
            bsplit(v0.z, Hh.s[2], Ll.s[2]); bsplit(v0.w, Hh.s[3], Ll.s[3]);
            bsplit(v1.x, Hh.s[4], Ll.s[4]); bsplit(v1.y, Hh.s[5], Ll.s[5]);
            bsplit(v1.z, Hh.s[6], Ll.s[6]); bsplit(v1.w, Hh.s[7], Ll.s[7]);
            *(uint4*)(Ah + r * APITCH + sub * 8) = Hh.u;
            *(uint4*)(Al + r * APITCH + sub * 8) = Ll.u;
        } else {
#pragma unroll
            for (int jj = 0; jj < 2; ++jj) {
                int j = tid + jj * 256;
                int part = j >> 8;
                int r = (j & 255) >> 2, sub = j & 3;
                int grow = row0 + r;
                const unsigned short* s = (part ? Xlo : Xhi) + (size_t)grow * K + kk + sub * 8;
                unsigned short* dl = (part ? Al : Ah) + r * APITCH + sub * 8;
                uint4 v = make_uint4(0u, 0u, 0u, 0u);
                if (grow < N_NODES) v = *(const uint4*)s;
                *(uint4*)dl = v;
            }
        }
        __syncthreads();

        const unsigned short* wb_h = WThi + (size_t)(kk >> 5) * 8192;
        const unsigned short* wb_l = WTlo + (size_t)(kk >> 5) * 8192;
        short8 bh[2][2], bo[2][2];
#pragma unroll
        for (int c = 0; c < 2; ++c)
#pragma unroll
            for (int o = 0; o < 2; ++o) {
                size_t off = (size_t)o * 4096 + (size_t)(wv * 2 + c) * 512 + (size_t)lane * 8;
                bh[c][o] = *(const short8*)(wb_h + off);
                bo[c][o] = *(const short8*)(wb_l + off);
            }
#pragma unroll
        for (int r = 0; r < 4; ++r) {
            int rl = r * 16 + n16;
            short8 ah = *(const short8*)(Ah + rl * APITCH + quad * 8);
            short8 al = *(const short8*)(Al + rl * APITCH + quad * 8);
#pragma unroll
            for (int c = 0; c < 2; ++c)
#pragma unroll
                for (int o = 0; o < 2; ++o) {
                    f32x4 t = acc[r][c][o];
                    t = __builtin_amdgcn_mfma_f32_16x16x32_bf16(ah, bh[c][o], t, 0, 0, 0);
                    t = __builtin_amdgcn_mfma_f32_16x16x32_bf16(ah, bo[c][o], t, 0, 0, 0);
                    t = __builtin_amdgcn_mfma_f32_16x16x32_bf16(al, bh[c][o], t, 0, 0, 0);
                    acc[r][c][o] = t;
                }
        }
        __syncthreads();
    }

    // epilogue: C/D layout col=lane&15, row=quad*4+reg; store fp16
#pragma unroll
    for (int r = 0; r < 4; ++r)
#pragma unroll
        for (int c = 0; c < 2; ++c)
#pragma unroll
            for (int o = 0; o < 2; ++o) {
                int col = wv * 32 + c * 16 + n16;
                float bb = (o ? br : bl)[col];
                unsigned short* O = o ? OR_ : OL;
#pragma unroll
                for (int g = 0; g < 4; ++g) {
                    int grow = row0 + r * 16 + quad * 4 + g;
                    if (grow < N_NODES) {
                        __half hv = __float2half(acc[r][c][o][g] + bb);
                        O[(size_t)grow * 128 + col] = *(unsigned short*)&hv;
                    }
                }
            }
}

__global__ __launch_bounds__(256, 4) void k_gemm_f32(
    const float* __restrict__ Xf,
    const unsigned short* __restrict__ WThi, const unsigned short* __restrict__ WTlo,
    const float* __restrict__ bl, const float* __restrict__ br,
    unsigned short* __restrict__ OL, unsigned short* __restrict__ OR_, int K)
{
    __shared__ __align__(16) unsigned short Ah[64 * APITCH];
    __shared__ __align__(16) unsigned short Al[64 * APITCH];
    gemm_body<true>(Ah, Al, Xf, nullptr, nullptr, WThi, WTlo, bl, br, OL, OR_, K, blockIdx.x);
}

__global__ __launch_bounds__(256, 4) void k_gemm_mfma(
    const unsigned short* __restrict__ Xhi, const unsigned short* __restrict__ Xlo,
    const unsigned short* __restrict__ WThi, const unsigned short* __restrict__ WTlo,
    const float* __restrict__ bl, const float* __restrict__ br,
    unsigned short* __restrict__ OL, unsigned short* __restrict__ OR_, int K)
{
    __shared__ __align__(16) unsigned short Ah[64 * APITCH];
    __shared__ __align__(16) unsigned short Al[64 * APITCH];
    gemm_body<false>(Ah, Al, nullptr, Xhi, Xlo, WThi, WTlo, bl, br, OL, OR_, K, blockIdx.x);
}

// ---------------------------------------------------------------- edge phase
// 16-lane butterfly sum on the VALU pipe via DPP (no ds_swizzle / lgkmcnt).
__device__ __forceinline__ float red16dpp(float v) {
    v += __int_as_float(__builtin_amdgcn_update_dpp(
             0, __float_as_int(v), 0xB1, 0xF, 0xF, true));   // quad_perm [1,0,3,2]
    v += __int_as_float(__builtin_amdgcn_update_dpp(
             0, __float_as_int(v), 0x4E, 0xF, 0xF, true));   // quad_perm [2,3,0,1]
    v += __int_as_float(__builtin_amdgcn_update_dpp(
             0, __float_as_int(v), 0x141, 0xF, 0xF, true));  // row_half_mirror
    v += __int_as_float(__builtin_amdgcn_update_dpp(
             0, __float_as_int(v), 0x140, 0xF, 0xF, true));  // row_mirror
    return v;
}

// logit partial in NATIVE fp16: leaky(x+r) via v_pk_add/mul/max_f16, then
// att·leaky via v_dot2_f32_f16 (f32 accumulate, built-in cvt). Replaces
// 8x v_cvt + ~20 pk-f32 per edge with 12 pk-f16 + 4 dot2.
__device__ __forceinline__ float dot8lk_h(uint4 u, const h2 r[4], const h2 a[4]) {
    const h2 ns = { (_Float16)NEG_SLOPE, (_Float16)NEG_SLOPE };
    float s = 0.f;
    h2 x0 = __builtin_bit_cast(h2, u.x);
    h2 x1 = __builtin_bit_cast(h2, u.y);
    h2 x2 = __builtin_bit_cast(h2, u.z);
    h2 x3 = __builtin_bit_cast(h2, u.w);
    h2 e0 = x0 + r[0];
    h2 e1 = x1 + r[1];
    h2 e2 = x2 + r[2];
    h2 e3 = x3 + r[3];
    h2 l0 = __builtin_elementwise_max(e0, e0 * ns);
    h2 l1 = __builtin_elementwise_max(e1, e1 * ns);
    h2 l2 = __builtin_elementwise_max(e2, e2 * ns);
    h2 l3 = __builtin_elementwise_max(e3, e3 * ns);
    s = __builtin_amdgcn_fdot2(l0, a[0], s, false);
    s = __builtin_amdgcn_fdot2(l1, a[1], s, false);
    s = __builtin_amdgcn_fdot2(l2, a[2], s, false);
    s = __builtin_amdgcn_fdot2(l3, a[3], s, false);
    return s;
}

// One wave per destination node; 4 quarters of 16 lanes each process a
// different incoming edge. R4's 1-deep pipeline (R6's 2-wide regressed:
// rotate-state movs + occupancy dip cost more than the 2nd in-flight load
// saved). Logit math in fp16 (see dot8lk_h); acc update f32 via fma_mix.
__global__ __launch_bounds__(256) void k_edge(
    const unsigned short* __restrict__ xl, const unsigned short* __restrict__ xr,
    const float* __restrict__ att, const float* __restrict__ bias,
    const int* __restrict__ offsets, const int* __restrict__ col_src,
    unsigned short* __restrict__ outHi, unsigned short* __restrict__ outLo)
{
    int d = blockIdx.x * 4 + (threadIdx.x >> 6);
    if (d >= N_NODES) return;
    const int lane = threadIdx.x & 63;
    const int q = lane >> 4;
    const int t = lane & 15;
    const size_t dim0 = (size_t)t * 8;

    // r row + att in fp16 (h2 x4)
    h2 rr[4], aa[4];
    {
        uint4 ur = *(const uint4*)(xr + (size_t)d * 128 + dim0);
        rr[0] = __builtin_bit_cast(h2, ur.x);
        rr[1] = __builtin_bit_cast(h2, ur.y);
        rr[2] = __builtin_bit_cast(h2, ur.z);
        rr[3] = __builtin_bit_cast(h2, ur.w);
        const float4 a0 = *(const float4*)(att + dim0);
        const float4 a1 = *(const float4*)(att + dim0 + 4);
        h2 w0 = { (_Float16)a0.x, (_Float16)a0.y }; aa[0] = w0;
        h2 w1 = { (_Float16)a0.z, (_Float16)a0.w }; aa[1] = w1;
        h2 w2 = { (_Float16)a1.x, (_Float16)a1.y }; aa[2] = w2;
        h2 w3 = { (_Float16)a1.z, (_Float16)a1.w }; aa[3] = w3;
    }

    uint4 uxs = *(const uint4*)(xl + (size_t)d * 128 + dim0);
    float sl = red16dpp(dot8lk_h(uxs, rr, aa));   // identical in all 64 lanes

    // deferred-max online softmax; every quarter starts at the self-loop logit.
    float m = sl, thr = sl + 8.f;
    float lsum = (q == 0) ? 1.f : 0.f;
    f32x2 acc[4];
    {
        float2 sa = __half22float2(*(__half2*)&uxs.x);
        float2 sb = __half22float2(*(__half2*)&uxs.y);
        float2 sc_ = __half22float2(*(__half2*)&uxs.z);
        float2 sd = __half22float2(*(__half2*)&uxs.w);
        f32x2 z = {0.f, 0.f};
        f32x2 v0 = {sa.x, sa.y}; acc[0] = (q == 0) ? v0 : z;
        f32x2 v1 = {sb.x, sb.y}; acc[1] = (q == 0) ? v1 : z;
        f32x2 v2 = {sc_.x, sc_.y}; acc[2] = (q == 0) ? v2 : z;
        f32x2 v3 = {sd.x, sd.y}; acc[3] = (q == 0) ? v3 : z;
    }

    const int ibeg = offsets[d], iend = offsets[d + 1];
    // 1-deep pipeline: row A in flight, src index B in flight
    int ia = ibeg + q;
    bool vA = ia < iend;
    int sA = vA ? col_src[ia] : d;
    uint4 uA = *(const uint4*)(xl + (size_t)sA * 128 + dim0);
    int ib = ia + 4;
    bool vB = ib < iend;
    int sB = vB ? col_src[ib] : d;

    for (int base = ibeg; base < iend; base += 4) {
        uint4 uB = *(const uint4*)(xl + (size_t)sB * 128 + dim0);
        int ic = base + 8 + q;
        bool vC = ic < iend;
        int sC = vC ? col_src[ic] : d;

        float logit = red16dpp(dot8lk_h(uA, rr, aa));   // quarter-uniform
        if (__builtin_expect(logit > thr, 0)) {         // rare rescale path
            float sc = __expf(m - logit);
            lsum *= sc;
#pragma unroll
            for (int j = 0; j < 4; ++j) acc[j] = acc[j] * sc;
            m = logit; thr = logit + 8.f;
        }
        float w = vA ? __expf(logit - m) : 0.f;         // <= e^8
        lsum += w;
        // acc += w * x  (half source -> v_fma_mix_f32 pattern)
        {
            __half2* hp = (__half2*)&uA;
#pragma unroll
            for (int j = 0; j < 4; ++j) {
                float2 xf = __half22float2(hp[j]);
                acc[j].x = fmaf(xf.x, w, acc[j].x);
                acc[j].y = fmaf(xf.y, w, acc[j].y);
            }
        }

        uA = uB; vA = vB; sB = sC; vB = vC;             // rotate pipeline
    }

    // merge the 4 quarters (each holds partials relative to its own m)
    float M = m;
    M = fmaxf(M, __shfl_xor(M, 16));
    M = fmaxf(M, __shfl_xor(M, 32));
    float sc = __expf(m - M);
    lsum *= sc;
    f32x2 sc2 = {sc, sc};
#pragma unroll
    for (int j = 0; j < 4; ++j) acc[j] = acc[j] * sc2;
#pragma unroll
    for (int off = 16; off <= 32; off <<= 1) {
        lsum += __shfl_xor(lsum, off);
#pragma unroll
        for (int j = 0; j < 4; ++j) {
            acc[j].x += __shfl_xor(acc[j].x, off);
            acc[j].y += __shfl_xor(acc[j].y, off);
        }
    }

    if (q == 0) {
        float inv = 1.f / lsum;
        const float4 b0 = *(const float4*)(bias + dim0);
        const float4 b1 = *(const float4*)(bias + dim0 + 4);
        float bv[8] = {b0.x, b0.y, b0.z, b0.w, b1.x, b1.y, b1.z, b1.w};
        float v[8];
#pragma unroll
        for (int j = 0; j < 4; ++j) {
            v[2 * j]     = fmaxf(fmaf(acc[j].x, inv, bv[2 * j]), 0.f);
            v[2 * j + 1] = fmaxf(fmaf(acc[j].y, inv, bv[2 * j + 1]), 0.f);
        }
        union { unsigned short s[8]; uint4 u; } Hh, Ll;
#pragma unroll
        for (int i2 = 0; i2 < 8; ++i2) bsplit(v[i2], Hh.s[i2], Ll.s[i2]);
        *(uint4*)(outHi + (size_t)d * 128 + dim0) = Hh.u;
        *(uint4*)(outLo + (size_t)d * 128 + dim0) = Ll.u;
    }
}

// ---------------------------------------------------------------- pooling
__global__ __launch_bounds__(256) void k_pool(
    const unsigned short* __restrict__ hHi, const unsigned short* __restrict__ hLo,
    const int* __restrict__ batch,
    float* __restrict__ psum, float* __restrict__ pcnt)
{
    const int tid = threadIdx.x;
    const int tx = tid & 31;
    const int ty = tid >> 5;
    const int n0 = blockIdx.x * 64;
    const int d0 = tx * 4;

    float4 acc = make_float4(0.f, 0.f, 0.f, 0.f);
    int cur = -1, crun = 0;
#pragma unroll
    for (int it = 0; it < 8; ++it) {
        int n = n0 + it * 8 + ty;
        if (n < N_NODES) {
            int g = batch[n];
            if (g != cur) {
                if (cur >= 0) {
                    atomicAdd(&psum[cur * 128 + d0 + 0], acc.x);
                    atomicAdd(&psum[cur * 128 + d0 + 1], acc.y);
                    atomicAdd(&psum[cur * 128 + d0 + 2], acc.z);
                    atomicAdd(&psum[cur * 128 + d0 + 3], acc.w);
                    if (tx == 0) atomicAdd(&pcnt[cur], (float)crun);
                }
                cur = g; acc = make_float4(0.f, 0.f, 0.f, 0.f); crun = 0;
            }
            ushort4 h = *(const ushort4*)(hHi + (size_t)n * 128 + d0);
            ushort4 l = *(const ushort4*)(hLo + (size_t)n * 128 + d0);
            acc.x += bjoin(h.x, l.x);
            acc.y += bjoin(h.y, l.y);
            acc.z += bjoin(h.z, l.z);
            acc.w += bjoin(h.w, l.w);
            crun++;
        }
    }
    if (cur >= 0) {
        atomicAdd(&psum[cur * 128 + d0 + 0], acc.x);
        atomicAdd(&psum[cur * 128 + d0 + 1], acc.y);
        atomicAdd(&psum[cur * 128 + d0 + 2], acc.z);
        atomicAdd(&psum[cur * 128 + d0 + 3], acc.w);
        if (tx == 0) atomicAdd(&pcnt[cur], (float)crun);
    }
}

// ---------------------------------------------------------------- head
__global__ __launch_bounds__(256) void k_head(
    const float* __restrict__ psum, const float* __restrict__ pcnt,
    const float* __restrict__ Wlin, const float* __restrict__ blin,
    float* __restrict__ out)
{
    int g = blockIdx.x * 4 + (threadIdx.x >> 6);
    if (g >= N_GRAPH) return;
    int lane = threadIdx.x & 63;
    float c = fmaxf(pcnt[g], 1.f);
    float2 s = *(const float2*)(psum + (size_t)g * 128 + lane * 2);
    float p = (s.x * Wlin[lane * 2] + s.y * Wlin[lane * 2 + 1]) / c;
#pragma unroll
    for (int off = 32; off > 0; off >>= 1) p += __shfl_xor(p, off);
    if (lane == 0) out[g] = p + blin[0];
}

// ---------------------------------------------------------------- launch
extern "C" void kernel_launch(void* const* d_in, const int* in_sizes, int n_in,
                              void* d_out, int out_size, void* d_ws, size_t ws_size,
                              hipStream_t stream) {
    const float* x     = (const float*)d_in[0];
    const int*   ei    = (const int*)d_in[1];
    const int*   batch = (const int*)d_in[3];
    const float* Wl1 = (const float*)d_in[4],  *bl1 = (const float*)d_in[5];
    const float* Wr1 = (const float*)d_in[6],  *br1 = (const float*)d_in[7];
    const float* att1= (const float*)d_in[8],  *b1  = (const float*)d_in[9];
    const float* Wl2 = (const float*)d_in[10], *bl2 = (const float*)d_in[11];
    const float* Wr2 = (const float*)d_in[12], *br2 = (const float*)d_in[13];
    const float* att2= (const float*)d_in[14], *b2  = (const float*)d_in[15];
    const float* Wlin= (const float*)d_in[16], *blin= (const float*)d_in[17];
    float* out = (float*)d_out;

    const int* src = ei;
    const int* dst = ei + N_EDGES;

    char* p = (char*)d_ws;
    auto carve = [&](size_t bytes) {
        void* r = (void*)p;
        p += (bytes + 255) & ~(size_t)255;
        return r;
    };
    unsigned short* bufA   = (unsigned short*)carve((size_t)N_NODES * 128 * 2); // xl fp16
    unsigned short* bufB   = (unsigned short*)carve((size_t)N_NODES * 128 * 2); // xr fp16
    unsigned short* Hhi    = (unsigned short*)carve((size_t)N_NODES * 128 * 2);
    unsigned short* Hlo    = (unsigned short*)carve((size_t)N_NODES * 128 * 2);
    unsigned short* WThi   = (unsigned short*)carve(49152 * 2);
    unsigned short* WTlo   = (unsigned short*)carve(49152 * 2);
    int*            offsets= (int*)carve((size_t)(N_NODES + 1) * 4);
    int*            lrank  = (int*)carve((size_t)N_EDGES * 4);
    int*            bcnt   = (int*)carve((size_t)NBB * 4);
    int*            bbase  = (int*)carve((size_t)NBB * 4);
    int*            partials=(int*)carve(SCANA_NB * 4);
    unsigned*       ebin   = (unsigned*)carve((size_t)N_EDGES * 4);
    int*            col_src= (int*)carve((size_t)N_EDGES * 4);
    // zero region: psum | pcnt
    char* zb = (char*)carve(262144 + 2048);
    float* psum   = (float*)zb;
    float* pcnt   = (float*)(zb + 262144);
    const size_t zbytes = 262144 + 2048;

    hipMemsetAsync(zb, 0, zbytes, stream);

    // prepW + bin1 (LDS histogram, no global atomics)
    k_prep<<<NB_PW + NBLK1, 256, 0, stream>>>(
        Wl1, Wr1, Wl2, Wr2, dst, WThi, WTlo, lrank, bcnt);

    // layer-1 GEMM (K=64) straight from fp32 x
    k_gemm_f32<<<GB_GEMM, 256, 0, stream>>>(x, WThi, WTlo,
                                            bl1, br1, bufA, bufB, F_IN);

    // CSR build: scan bcnt -> scatter to bin-sorted -> per-bin offsets+fill
    k_scanA<<<SCANA_NB, 256, 0, stream>>>(bcnt, bbase, partials);
    k_scanB<<<SCANA_NB, 256, 0, stream>>>(bbase, partials);
    k_bin2 <<<(N_EDGES + 255) / 256, 256, 0, stream>>>(src, dst, lrank, bbase, ebin);
    k_bin3 <<<NBIN, 256, 0, stream>>>(ebin, bbase, offsets, col_src);

    k_edge<<<(N_NODES + 3) / 4, 256, 0, stream>>>(
        bufA, bufB, att1, b1, offsets, col_src, Hhi, Hlo);
    // layer 2 (K=128)
    k_gemm_mfma<<<GB_GEMM, 256, 0, stream>>>(Hhi, Hlo, WThi + 16384, WTlo + 16384,
                                             bl2, br2, bufA, bufB, H_DIM);
    k_edge<<<(N_NODES + 3) / 4, 256, 0, stream>>>(
        bufA, bufB, att2, b2, offsets, col_src, Hhi, Hlo);
    // pool + head
    k_pool<<<(N_NODES + 63) / 64, 256, 0, stream>>>(Hhi, Hlo, batch, psum, pcnt);
    k_head<<<(N_GRAPH + 3) / 4, 256, 0, stream>>>(psum, pcnt, Wlin, blin, out);
}

// Round 8
// 258.212 us; speedup vs baseline: 1.0601x; 1.0601x over previous
//
#include <hip/hip_runtime.h>
#include <hip/hip_fp16.h>
#include <math.h>

#define N_NODES 50000
#define N_EDGES 800000
#define F_IN    64
#define H_DIM   128
#define N_GRAPH 512
#define NEG_SLOPE 0.2f

typedef __attribute__((ext_vector_type(8))) short short8;   // 8 bf16 (4 VGPRs)
typedef __attribute__((ext_vector_type(4))) float f32x4;
typedef __attribute__((ext_vector_type(2))) float f32x2;
typedef _Float16 h2 __attribute__((ext_vector_type(2)));    // half2 (v_pk_*_f16)
typedef _Float16 h8 __attribute__((ext_vector_type(8)));    // 8 fp16 (4 VGPRs, MFMA frag)

// ---- counting-sort geometry: bins of 256 dst nodes, 2048-edge bin1 blocks
#define NBIN   196                      // ceil(50000/256)
#define NBLK1  391                      // ceil(800000/2048)
#define NBB    (NBIN * NBLK1)           // 76636 (bin-major count matrix)
#define SCANA_NB ((NBB + 255) / 256)    // 300

// fp32 -> bf16(hi) + bf16(lo), truncation split (residual ~2^-16 relative)
__device__ __forceinline__ void bsplit(float v, unsigned short& h, unsigned short& l) {
    unsigned u = __float_as_uint(v);
    h = (unsigned short)(u >> 16);
    float hf = __uint_as_float(u & 0xFFFF0000u);
    float r = v - hf;
    l = (unsigned short)(__float_as_uint(r) >> 16);
}

// ------------------- prep: prepW(frag-major swizzle) | bin1 (LDS histogram)
// Layer-1 W -> bf16 split (3-pass f32-accurate GEMM from fp32 x).
// Layer-2 W -> single fp16 table (layer 2 runs native fp16 MFMA, 1 pass:
// the pipeline's absmax is already set by fp16 quantization of the edge
// inputs, so bf16-split precision on this path was wasted work).
#define NB_PW 192
__global__ __launch_bounds__(256) void k_prep(
    const float* __restrict__ Wl1, const float* __restrict__ Wr1,
    const float* __restrict__ Wl2, const float* __restrict__ Wr2,
    const int* __restrict__ dst,
    unsigned short* __restrict__ WThi, unsigned short* __restrict__ WTlo,
    unsigned short* __restrict__ WT2f,
    int* __restrict__ lrank, int* __restrict__ bcnt)
{
    __shared__ int cnt_lds[NBIN];
    const int bid = blockIdx.x, tid = threadIdx.x;
    if (bid < NB_PW) {
        int idx = bid * 256 + tid;   // 0..49151
        if (idx < 49152) {
            const float* W; int K, li, base, o;
            if (idx < 8192)       { W = Wl1; K = 64;  li = idx;         base = 0;     o = 0; }
            else if (idx < 16384) { W = Wr1; K = 64;  li = idx - 8192;  base = 0;     o = 1; }
            else if (idx < 32768) { W = Wl2; K = 128; li = idx - 16384; base = 16384; o = 0; }
            else                  { W = Wr2; K = 128; li = idx - 32768; base = 16384; o = 1; }
            int c = li / K, k = li - c * K;
            int g = c >> 4, n16 = c & 15;
            int kkblk = k >> 5, quad = (k >> 3) & 3, j = k & 7;
            int off = base + kkblk * 8192 + o * 4096 + g * 512 + (quad * 16 + n16) * 8 + j;
            float wv = W[k * 128 + c];
            if (base == 0) {
                unsigned short h, l;
                bsplit(wv, h, l);
                WThi[off] = h; WTlo[off] = l;
            } else {
                __half hv = __float2half(wv);
                WT2f[off - 16384] = *(unsigned short*)&hv;
            }
        }
    } else {
        const int b2 = bid - NB_PW;    // 0..390
        if (tid < NBIN) cnt_lds[tid] = 0;
        __syncthreads();
#pragma unroll
        for (int it = 0; it < 8; ++it) {
            int e = b2 * 2048 + it * 256 + tid;
            if (e < N_EDGES) {
                int d = dst[e];
                lrank[e] = atomicAdd(&cnt_lds[d >> 8], 1);
            }
        }
        __syncthreads();
        if (tid < NBIN) bcnt[tid * NBLK1 + b2] = cnt_lds[tid];
    }
}

// ---------------------------------------------------------------- scans
__global__ __launch_bounds__(256) void k_scanA(const int* __restrict__ bcnt,
                                               int* __restrict__ bbase,
                                               int* __restrict__ partials) {
    __shared__ int s[256];
    int t = threadIdx.x, gid = blockIdx.x * 256 + t;
    int v = (gid < NBB) ? bcnt[gid] : 0;
    s[t] = v;
    __syncthreads();
    for (int off = 1; off < 256; off <<= 1) {
        int x = (t >= off) ? s[t - off] : 0;
        __syncthreads();
        s[t] += x;
        __syncthreads();
    }
    if (gid < NBB) bbase[gid] = s[t] - v;
    if (t == 255) partials[blockIdx.x] = s[t];
}

__global__ __launch_bounds__(256) void k_scanB(int* __restrict__ bbase,
                                               const int* __restrict__ partials) {
    __shared__ int red[256];
    const int t = threadIdx.x, b = blockIdx.x;
    int acc = 0;
    for (int j = t; j < b; j += 256) acc += partials[j];
    red[t] = acc;
    __syncthreads();
    for (int off = 128; off > 0; off >>= 1) {
        if (t < off) red[t] += red[t + off];
        __syncthreads();
    }
    int base = red[0];
    int gid = b * 256 + t;
    if (gid < NBB) bbase[gid] += base;
}

// scatter edges into bin-sorted order; pack src (16b) | dst&255 (8b)
__global__ __launch_bounds__(256) void k_bin2(const int* __restrict__ src,
                                              const int* __restrict__ dst,
                                              const int* __restrict__ lrank,
                                              const int* __restrict__ bbase,
                                              unsigned* __restrict__ ebin) {
    int e = blockIdx.x * 256 + threadIdx.x;
    if (e < N_EDGES) {
        int d = dst[e];
        int pos = bbase[(d >> 8) * NBLK1 + (e >> 11)] + lrank[e];
        ebin[pos] = (unsigned)src[e] | ((unsigned)(d & 255) << 16);
    }
}

// per-bin: exact per-node counts (LDS) -> in-bin scan -> offsets + col_src.
__global__ __launch_bounds__(256) void k_bin3(const unsigned* __restrict__ ebin,
                                              const int* __restrict__ bbase,
                                              int* __restrict__ offsets,
                                              int* __restrict__ col_src) {
    __shared__ int cnt2[256];
    __shared__ int sc[256];
    __shared__ int cur[256];
    const int b = blockIdx.x, t = threadIdx.x;
    const int lo = bbase[b * NBLK1];
    const int hi = (b == NBIN - 1) ? N_EDGES : bbase[(b + 1) * NBLK1];

    cnt2[t] = 0;
    __syncthreads();
    for (int pos = lo + t; pos < hi; pos += 256) {
        unsigned u = ebin[pos];
        atomicAdd(&cnt2[u >> 16], 1);
    }
    __syncthreads();
    int v = cnt2[t];
    sc[t] = v;
    __syncthreads();
    for (int off = 1; off < 256; off <<= 1) {
        int x = (t >= off) ? sc[t - off] : 0;
        __syncthreads();
        sc[t] += x;
        __syncthreads();
    }
    int myoff = lo + sc[t] - v;            // exclusive in-bin prefix + bin base
    int node = b * 256 + t;
    if (node < N_NODES) offsets[node] = myoff;
    cur[t] = myoff;
    if (b == NBIN - 1 && t == 0) offsets[N_NODES] = N_EDGES;
    __syncthreads();
    for (int pos = lo + t; pos < hi; pos += 256) {
        unsigned u = ebin[pos];
        int p = atomicAdd(&cur[u >> 16], 1);
        col_src[p] = (int)(u & 0xFFFFu);
    }
}

// ---------------------------------------------------------------- GEMM 1
// 3-pass bf16-split straight from fp32 x (bit-identical to prepX path).
#define APITCH 40
#define GB_GEMM ((N_NODES + 63) / 64)   // 782

__global__ __launch_bounds__(256, 4) void k_gemm_f32(
    const float* __restrict__ Xf,
    const unsigned short* __restrict__ WThi, const unsigned short* __restrict__ WTlo,
    const float* __restrict__ bl, const float* __restrict__ br,
    unsigned short* __restrict__ OL, unsigned short* __restrict__ OR_, int K)
{
    __shared__ __align__(16) unsigned short Ah[64 * APITCH];
    __shared__ __align__(16) unsigned short Al[64 * APITCH];

    const int tid  = threadIdx.x;
    const int wv   = tid >> 6;        // wave: cols [wv*32, wv*32+32)
    const int lane = tid & 63;
    const int n16  = lane & 15;
    const int quad = lane >> 4;
    const int row0 = blockIdx.x * 64;

    f32x4 acc[4][2][2];
#pragma unroll
    for (int r = 0; r < 4; ++r)
#pragma unroll
        for (int c = 0; c < 2; ++c)
#pragma unroll
            for (int o = 0; o < 2; ++o) acc[r][c][o] = (f32x4)0.f;

    for (int kk = 0; kk < K; kk += 32) {
        {
            int r = tid >> 2, sub = tid & 3;
            int grow = row0 + r;
            float4 v0 = make_float4(0.f, 0.f, 0.f, 0.f);
            float4 v1 = make_float4(0.f, 0.f, 0.f, 0.f);
            if (grow < N_NODES) {
                const float* s = Xf + (size_t)grow * K + kk + sub * 8;
                v0 = *(const float4*)s;
                v1 = *(const float4*)(s + 4);
            }
            union { unsigned short s[8]; uint4 u; } Hh, Ll;
            bsplit(v0.x, Hh.s[0], Ll.s[0]); bsplit(v0.y, Hh.s[1], Ll.s[1]);
            bsplit(v0.z, Hh.s[2], Ll.s[2]); bsplit(v0.w, Hh.s[3], Ll.s[3]);
            bsplit(v1.x, Hh.s[4], Ll.s[4]); bsplit(v1.y, Hh.s[5], Ll.s[5]);
            bsplit(v1.z, Hh.s[6], Ll.s[6]); bsplit(v1.w, Hh.s[7], Ll.s[7]);
            *(uint4*)(Ah + r * APITCH + sub * 8) = Hh.u;
            *(uint4*)(Al + r * APITCH + sub * 8) = Ll.u;
        }
        __syncthreads();

        const unsigned short* wb_h = WThi + (size_t)(kk >> 5) * 8192;
        const unsigned short* wb_l = WTlo + (size_t)(kk >> 5) * 8192;
        short8 bh[2][2], bo[2][2];
#pragma unroll
        for (int c = 0; c < 2; ++c)
#pragma unroll
            for (int o = 0; o < 2; ++o) {
                size_t off = (size_t)o * 4096 + (size_t)(wv * 2 + c) * 512 + (size_t)lane * 8;
                bh[c][o] = *(const short8*)(wb_h + off);
                bo[c][o] = *(const short8*)(wb_l + off);
            }
#pragma unroll
        for (int r = 0; r < 4; ++r) {
            int rl = r * 16 + n16;
            short8 ah = *(const short8*)(Ah + rl * APITCH + quad * 8);
            short8 al = *(const short8*)(Al + rl * APITCH + quad * 8);
#pragma unroll
            for (int c = 0; c < 2; ++c)
#pragma unroll
                for (int o = 0; o < 2; ++o) {
                    f32x4 t = acc[r][c][o];
                    t = __builtin_amdgcn_mfma_f32_16x16x32_bf16(ah, bh[c][o], t, 0, 0, 0);
                    t = __builtin_amdgcn_mfma_f32_16x16x32_bf16(ah, bo[c][o], t, 0, 0, 0);
                    t = __builtin_amdgcn_mfma_f32_16x16x32_bf16(al, bh[c][o], t, 0, 0, 0);
                    acc[r][c][o] = t;
                }
        }
        __syncthreads();
    }

#pragma unroll
    for (int r = 0; r < 4; ++r)
#pragma unroll
        for (int c = 0; c < 2; ++c)
#pragma unroll
            for (int o = 0; o < 2; ++o) {
                int col = wv * 32 + c * 16 + n16;
                float bb = (o ? br : bl)[col];
                unsigned short* O = o ? OR_ : OL;
#pragma unroll
                for (int g = 0; g < 4; ++g) {
                    int grow = row0 + r * 16 + quad * 4 + g;
                    if (grow < N_NODES) {
                        __half hv = __float2half(acc[r][c][o][g] + bb);
                        O[(size_t)grow * 128 + col] = *(unsigned short*)&hv;
                    }
                }
            }
}

// ---------------------------------------------------------------- GEMM 2
// Native fp16 single-pass MFMA (K=128). Fragment layout is dtype-independent
// (same as bf16 16x16x32), so the same swizzled-W addressing applies.
__global__ __launch_bounds__(256, 4) void k_gemm_f16(
    const unsigned short* __restrict__ X,       // H, fp16 [N,128]
    const unsigned short* __restrict__ WT2f,
    const float* __restrict__ bl, const float* __restrict__ br,
    unsigned short* __restrict__ OL, unsigned short* __restrict__ OR_)
{
    __shared__ __align__(16) unsigned short Ah[64 * APITCH];

    const int tid  = threadIdx.x;
    const int wv   = tid >> 6;
    const int lane = tid & 63;
    const int n16  = lane & 15;
    const int quad = lane >> 4;
    const int row0 = blockIdx.x * 64;

    f32x4 acc[4][2][2];
#pragma unroll
    for (int r = 0; r < 4; ++r)
#pragma unroll
        for (int c = 0; c < 2; ++c)
#pragma unroll
            for (int o = 0; o < 2; ++o) acc[r][c][o] = (f32x4)0.f;

    for (int kk = 0; kk < 128; kk += 32) {
        {
            int r = tid >> 2, sub = tid & 3;
            int grow = row0 + r;
            uint4 v = make_uint4(0u, 0u, 0u, 0u);
            if (grow < N_NODES)
                v = *(const uint4*)(X + (size_t)grow * 128 + kk + sub * 8);
            *(uint4*)(Ah + r * APITCH + sub * 8) = v;
        }
        __syncthreads();

        const unsigned short* wb = WT2f + (size_t)(kk >> 5) * 8192;
        h8 bf[2][2];
#pragma unroll
        for (int c = 0; c < 2; ++c)
#pragma unroll
            for (int o = 0; o < 2; ++o) {
                size_t off = (size_t)o * 4096 + (size_t)(wv * 2 + c) * 512 + (size_t)lane * 8;
                bf[c][o] = *(const h8*)(wb + off);
            }
#pragma unroll
        for (int r = 0; r < 4; ++r) {
            int rl = r * 16 + n16;
            h8 ah = *(const h8*)(Ah + rl * APITCH + quad * 8);
#pragma unroll
            for (int c = 0; c < 2; ++c)
#pragma unroll
                for (int o = 0; o < 2; ++o)
                    acc[r][c][o] = __builtin_amdgcn_mfma_f32_16x16x32_f16(
                        ah, bf[c][o], acc[r][c][o], 0, 0, 0);
        }
        __syncthreads();
    }

#pragma unroll
    for (int r = 0; r < 4; ++r)
#pragma unroll
        for (int c = 0; c < 2; ++c)
#pragma unroll
            for (int o = 0; o < 2; ++o) {
                int col = wv * 32 + c * 16 + n16;
                float bb = (o ? br : bl)[col];
                unsigned short* O = o ? OR_ : OL;
#pragma unroll
                for (int g = 0; g < 4; ++g) {
                    int grow = row0 + r * 16 + quad * 4 + g;
                    if (grow < N_NODES) {
                        __half hv = __float2half(acc[r][c][o][g] + bb);
                        O[(size_t)grow * 128 + col] = *(unsigned short*)&hv;
                    }
                }
            }
}

// ---------------------------------------------------------------- edge phase
__device__ __forceinline__ float red16dpp(float v) {
    v += __int_as_float(__builtin_amdgcn_update_dpp(
             0, __float_as_int(v), 0xB1, 0xF, 0xF, true));   // quad_perm [1,0,3,2]
    v += __int_as_float(__builtin_amdgcn_update_dpp(
             0, __float_as_int(v), 0x4E, 0xF, 0xF, true));   // quad_perm [2,3,0,1]
    v += __int_as_float(__builtin_amdgcn_update_dpp(
             0, __float_as_int(v), 0x141, 0xF, 0xF, true));  // row_half_mirror
    v += __int_as_float(__builtin_amdgcn_update_dpp(
             0, __float_as_int(v), 0x140, 0xF, 0xF, true));  // row_mirror
    return v;
}

// logit partial in NATIVE fp16: leaky(x+r) via v_pk_add/mul/max_f16, then
// att·leaky via v_dot2_f32_f16 (f32 accumulate, built-in cvt).
__device__ __forceinline__ float dot8lk_h(uint4 u, const h2 r[4], const h2 a[4]) {
    const h2 ns = { (_Float16)NEG_SLOPE, (_Float16)NEG_SLOPE };
    float s = 0.f;
    h2 x0 = __builtin_bit_cast(h2, u.x);
    h2 x1 = __builtin_bit_cast(h2, u.y);
    h2 x2 = __builtin_bit_cast(h2, u.z);
    h2 x3 = __builtin_bit_cast(h2, u.w);
    h2 e0 = x0 + r[0];
    h2 e1 = x1 + r[1];
    h2 e2 = x2 + r[2];
    h2 e3 = x3 + r[3];
    h2 l0 = __builtin_elementwise_max(e0, e0 * ns);
    h2 l1 = __builtin_elementwise_max(e1, e1 * ns);
    h2 l2 = __builtin_elementwise_max(e2, e2 * ns);
    h2 l3 = __builtin_elementwise_max(e3, e3 * ns);
    s = __builtin_amdgcn_fdot2(l0, a[0], s, false);
    s = __builtin_amdgcn_fdot2(l1, a[1], s, false);
    s = __builtin_amdgcn_fdot2(l2, a[2], s, false);
    s = __builtin_amdgcn_fdot2(l3, a[3], s, false);
    return s;
}

// One wave per destination node; 4 quarters of 16 lanes each process a
// different incoming edge. 1-deep pipeline; fp16 logit math; deferred-max
// softmax. Output: single fp16 row (layer-2 GEMM is fp16 now).
__global__ __launch_bounds__(256) void k_edge(
    const unsigned short* __restrict__ xl, const unsigned short* __restrict__ xr,
    const float* __restrict__ att, const float* __restrict__ bias,
    const int* __restrict__ offsets, const int* __restrict__ col_src,
    unsigned short* __restrict__ outH)
{
    int d = blockIdx.x * 4 + (threadIdx.x >> 6);
    if (d >= N_NODES) return;
    const int lane = threadIdx.x & 63;
    const int q = lane >> 4;
    const int t = lane & 15;
    const size_t dim0 = (size_t)t * 8;

    h2 rr[4], aa[4];
    {
        uint4 ur = *(const uint4*)(xr + (size_t)d * 128 + dim0);
        rr[0] = __builtin_bit_cast(h2, ur.x);
        rr[1] = __builtin_bit_cast(h2, ur.y);
        rr[2] = __builtin_bit_cast(h2, ur.z);
        rr[3] = __builtin_bit_cast(h2, ur.w);
        const float4 a0 = *(const float4*)(att + dim0);
        const float4 a1 = *(const float4*)(att + dim0 + 4);
        h2 w0 = { (_Float16)a0.x, (_Float16)a0.y }; aa[0] = w0;
        h2 w1 = { (_Float16)a0.z, (_Float16)a0.w }; aa[1] = w1;
        h2 w2 = { (_Float16)a1.x, (_Float16)a1.y }; aa[2] = w2;
        h2 w3 = { (_Float16)a1.z, (_Float16)a1.w }; aa[3] = w3;
    }

    uint4 uxs = *(const uint4*)(xl + (size_t)d * 128 + dim0);
    float sl = red16dpp(dot8lk_h(uxs, rr, aa));   // identical in all 64 lanes

    float m = sl, thr = sl + 8.f;
    float lsum = (q == 0) ? 1.f : 0.f;
    f32x2 acc[4];
    {
        float2 sa = __half22float2(*(__half2*)&uxs.x);
        float2 sb = __half22float2(*(__half2*)&uxs.y);
        float2 sc_ = __half22float2(*(__half2*)&uxs.z);
        float2 sd = __half22float2(*(__half2*)&uxs.w);
        f32x2 z = {0.f, 0.f};
        f32x2 v0 = {sa.x, sa.y}; acc[0] = (q == 0) ? v0 : z;
        f32x2 v1 = {sb.x, sb.y}; acc[1] = (q == 0) ? v1 : z;
        f32x2 v2 = {sc_.x, sc_.y}; acc[2] = (q == 0) ? v2 : z;
        f32x2 v3 = {sd.x, sd.y}; acc[3] = (q == 0) ? v3 : z;
    }

    const int ibeg = offsets[d], iend = offsets[d + 1];
    int ia = ibeg + q;
    bool vA = ia < iend;
    int sA = vA ? col_src[ia] : d;
    uint4 uA = *(const uint4*)(xl + (size_t)sA * 128 + dim0);
    int ib = ia + 4;
    bool vB = ib < iend;
    int sB = vB ? col_src[ib] : d;

    for (int base = ibeg; base < iend; base += 4) {
        uint4 uB = *(const uint4*)(xl + (size_t)sB * 128 + dim0);
        int ic = base + 8 + q;
        bool vC = ic < iend;
        int sC = vC ? col_src[ic] : d;

        float logit = red16dpp(dot8lk_h(uA, rr, aa));   // quarter-uniform
        if (__builtin_expect(logit > thr, 0)) {         // rare rescale path
            float sc = __expf(m - logit);
            lsum *= sc;
#pragma unroll
            for (int j = 0; j < 4; ++j) acc[j] = acc[j] * sc;
            m = logit; thr = logit + 8.f;
        }
        float w = vA ? __expf(logit - m) : 0.f;         // <= e^8
        lsum += w;
        {
            __half2* hp = (__half2*)&uA;
#pragma unroll
            for (int j = 0; j < 4; ++j) {
                float2 xf = __half22float2(hp[j]);
                acc[j].x = fmaf(xf.x, w, acc[j].x);
                acc[j].y = fmaf(xf.y, w, acc[j].y);
            }
        }

        uA = uB; vA = vB; sB = sC; vB = vC;             // rotate pipeline
    }

    float M = m;
    M = fmaxf(M, __shfl_xor(M, 16));
    M = fmaxf(M, __shfl_xor(M, 32));
    float sc = __expf(m - M);
    lsum *= sc;
    f32x2 sc2 = {sc, sc};
#pragma unroll
    for (int j = 0; j < 4; ++j) acc[j] = acc[j] * sc2;
#pragma unroll
    for (int off = 16; off <= 32; off <<= 1) {
        lsum += __shfl_xor(lsum, off);
#pragma unroll
        for (int j = 0; j < 4; ++j) {
            acc[j].x += __shfl_xor(acc[j].x, off);
            acc[j].y += __shfl_xor(acc[j].y, off);
        }
    }

    if (q == 0) {
        float inv = 1.f / lsum;
        const float4 b0 = *(const float4*)(bias + dim0);
        const float4 b1 = *(const float4*)(bias + dim0 + 4);
        float bv[8] = {b0.x, b0.y, b0.z, b0.w, b1.x, b1.y, b1.z, b1.w};
        union { __half2 h[4]; uint4 u; } O;
#pragma unroll
        for (int j = 0; j < 4; ++j) {
            float v0 = fmaxf(fmaf(acc[j].x, inv, bv[2 * j]), 0.f);
            float v1 = fmaxf(fmaf(acc[j].y, inv, bv[2 * j + 1]), 0.f);
            O.h[j] = __floats2half2_rn(v0, v1);
        }
        *(uint4*)(outH + (size_t)d * 128 + dim0) = O.u;
    }
}

// ---------------------------------------------------------------- pooling
__global__ __launch_bounds__(256) void k_pool(
    const unsigned short* __restrict__ H,
    const int* __restrict__ batch,
    float* __restrict__ psum, float* __restrict__ pcnt)
{
    const int tid = threadIdx.x;
    const int tx = tid & 31;
    const int ty = tid >> 5;
    const int n0 = blockIdx.x * 64;
    const int d0 = tx * 4;

    float4 acc = make_float4(0.f, 0.f, 0.f, 0.f);
    int cur = -1, crun = 0;
#pragma unroll
    for (int it = 0; it < 8; ++it) {
        int n = n0 + it * 8 + ty;
        if (n < N_NODES) {
            int g = batch[n];
            if (g != cur) {
                if (cur >= 0) {
                    atomicAdd(&psum[cur * 128 + d0 + 0], acc.x);
                    atomicAdd(&psum[cur * 128 + d0 + 1], acc.y);
                    atomicAdd(&psum[cur * 128 + d0 + 2], acc.z);
                    atomicAdd(&psum[cur * 128 + d0 + 3], acc.w);
                    if (tx == 0) atomicAdd(&pcnt[cur], (float)crun);
                }
                cur = g; acc = make_float4(0.f, 0.f, 0.f, 0.f); crun = 0;
            }
            uint2 hv = *(const uint2*)(H + (size_t)n * 128 + d0);
            float2 a = __half22float2(*(__half2*)&hv.x);
            float2 b = __half22float2(*(__half2*)&hv.y);
            acc.x += a.x; acc.y += a.y; acc.z += b.x; acc.w += b.y;
            crun++;
        }
    }
    if (cur >= 0) {
        atomicAdd(&psum[cur * 128 + d0 + 0], acc.x);
        atomicAdd(&psum[cur * 128 + d0 + 1], acc.y);
        atomicAdd(&psum[cur * 128 + d0 + 2], acc.z);
        atomicAdd(&psum[cur * 128 + d0 + 3], acc.w);
        if (tx == 0) atomicAdd(&pcnt[cur], (float)crun);
    }
}

// ---------------------------------------------------------------- head
__global__ __launch_bounds__(256) void k_head(
    const float* __restrict__ psum, const float* __restrict__ pcnt,
    const float* __restrict__ Wlin, const float* __restrict__ blin,
    float* __restrict__ out)
{
    int g = blockIdx.x * 4 + (threadIdx.x >> 6);
    if (g >= N_GRAPH) return;
    int lane = threadIdx.x & 63;
    float c = fmaxf(pcnt[g], 1.f);
    float2 s = *(const float2*)(psum + (size_t)g * 128 + lane * 2);
    float p = (s.x * Wlin[lane * 2] + s.y * Wlin[lane * 2 + 1]) / c;
#pragma unroll
    for (int off = 32; off > 0; off >>= 1) p += __shfl_xor(p, off);
    if (lane == 0) out[g] = p + blin[0];
}

// ---------------------------------------------------------------- launch
extern "C" void kernel_launch(void* const* d_in, const int* in_sizes, int n_in,
                              void* d_out, int out_size, void* d_ws, size_t ws_size,
                              hipStream_t stream) {
    const float* x     = (const float*)d_in[0];
    const int*   ei    = (const int*)d_in[1];
    const int*   batch = (const int*)d_in[3];
    const float* Wl1 = (const float*)d_in[4],  *bl1 = (const float*)d_in[5];
    const float* Wr1 = (const float*)d_in[6],  *br1 = (const float*)d_in[7];
    const float* att1= (const float*)d_in[8],  *b1  = (const float*)d_in[9];
    const float* Wl2 = (const float*)d_in[10], *bl2 = (const float*)d_in[11];
    const float* Wr2 = (const float*)d_in[12], *br2 = (const float*)d_in[13];
    const float* att2= (const float*)d_in[14], *b2  = (const float*)d_in[15];
    const float* Wlin= (const float*)d_in[16], *blin= (const float*)d_in[17];
    float* out = (float*)d_out;

    const int* src = ei;
    const int* dst = ei + N_EDGES;

    char* p = (char*)d_ws;
    auto carve = [&](size_t bytes) {
        void* r = (void*)p;
        p += (bytes + 255) & ~(size_t)255;
        return r;
    };
    unsigned short* bufA   = (unsigned short*)carve((size_t)N_NODES * 128 * 2); // xl fp16
    unsigned short* bufB   = (unsigned short*)carve((size_t)N_NODES * 128 * 2); // xr fp16
    unsigned short* H      = (unsigned short*)carve((size_t)N_NODES * 128 * 2); // fp16
    unsigned short* WThi   = (unsigned short*)carve(16384 * 2);
    unsigned short* WTlo   = (unsigned short*)carve(16384 * 2);
    unsigned short* WT2f   = (unsigned short*)carve(32768 * 2);
    int*            offsets= (int*)carve((size_t)(N_NODES + 1) * 4);
    int*            lrank  = (int*)carve((size_t)N_EDGES * 4);
    int*            bcnt   = (int*)carve((size_t)NBB * 4);
    int*            bbase  = (int*)carve((size_t)NBB * 4);
    int*            partials=(int*)carve(SCANA_NB * 4);
    unsigned*       ebin   = (unsigned*)carve((size_t)N_EDGES * 4);
    int*            col_src= (int*)carve((size_t)N_EDGES * 4);
    // zero region: psum | pcnt
    char* zb = (char*)carve(262144 + 2048);
    float* psum   = (float*)zb;
    float* pcnt   = (float*)(zb + 262144);
    const size_t zbytes = 262144 + 2048;

    hipMemsetAsync(zb, 0, zbytes, stream);

    // prepW (layer1 bf16-split, layer2 fp16) + bin1 (LDS histogram)
    k_prep<<<NB_PW + NBLK1, 256, 0, stream>>>(
        Wl1, Wr1, Wl2, Wr2, dst, WThi, WTlo, WT2f, lrank, bcnt);

    // layer-1 GEMM (K=64) straight from fp32 x, 3-pass bf16-split
    k_gemm_f32<<<GB_GEMM, 256, 0, stream>>>(x, WThi, WTlo,
                                            bl1, br1, bufA, bufB, F_IN);

    // CSR build: scan bcnt -> scatter to bin-sorted -> per-bin offsets+fill
    k_scanA<<<SCANA_NB, 256, 0, stream>>>(bcnt, bbase, partials);
    k_scanB<<<SCANA_NB, 256, 0, stream>>>(bbase, partials);
    k_bin2 <<<(N_EDGES + 255) / 256, 256, 0, stream>>>(src, dst, lrank, bbase, ebin);
    k_bin3 <<<NBIN, 256, 0, stream>>>(ebin, bbase, offsets, col_src);

    // edge layer 1 -> H (fp16)
    k_edge<<<(N_NODES + 3) / 4, 256, 0, stream>>>(
        bufA, bufB, att1, b1, offsets, col_src, H);
    // layer-2 GEMM: native fp16 single-pass
    k_gemm_f16<<<GB_GEMM, 256, 0, stream>>>(H, WT2f, bl2, br2, bufA, bufB);
    // edge layer 2 -> H (fp16)
    k_edge<<<(N_NODES + 3) / 4, 256, 0, stream>>>(
        bufA, bufB, att2, b2, offsets, col_src, H);
    // pool + head
    k_pool<<<(N_NODES + 63) / 64, 256, 0, stream>>>(H, batch, psum, pcnt);
    k_head<<<(N_GRAPH + 3) / 4, 256, 0, stream>>>(psum, pcnt, Wlin, blin, out);
}